// Round 3
// baseline (171.196 us; speedup 1.0000x reference)
//
#include <hip/hip_runtime.h>

// Quantum circuit sim, register-blocked. B=256 blocks (1/CU), 1024 thr/block.
// State: 2^14 amps. Thread t holds 16 amps in registers.
//   STD layout: amp index i = (t<<4)|r   -> bits[13:4]=t, bits[3:0]=r
//   TRN layout: i = (r<<10)|(lane<<4)|wave
// Wire w <-> bit (13-w)  (PennyLane: wire 0 most significant).
//   STD: wires 0-3 = wave bits, wires 4-9 = lane bits (shfl), wires 10-13 = reg
//   TRN: wires 0-3 = reg bits,  wires 4-9 = lane bits,        wires 10-13 = wave
// LDS slot swizzle: slot(i) = i ^ ((i>>6)&15)  (bank-conflict-free for all
// four access patterns used; verified per-pattern over the 64-lane wave).
// CNOT chain (prefix-xor perm): CNOT(4,5)..(12,13) composite inverse is
// x = y ^ ((y>>1) & 0x1FF), folded into the transpose-back gather.
//
// __launch_bounds__(1024, 4): 4 waves/EU => VGPR cap 128. Without the
// min-waves arg the allocator capped at 64 VGPRs and SPILLED amps[16] to
// scratch (R2: 150 MB HBM traffic/dispatch, 1.24 TB/s — the whole runtime).

#define NW      14
#define NSTATE  (1 << NW)
#define TPB     1024
#define NLAYERS 3
#define NGATES  (NLAYERS * NW)

__device__ __forceinline__ int swz(int i) { return i ^ ((i >> 6) & 15); }

// u[8] = {u00x,u00y, u01x,u01y, u10x,u10y, u11x,u11y}
__device__ __forceinline__ void pairgate(float2& a, float2& d, const float u[8]) {
    float2 na, nd;
    na.x = u[0]*a.x - u[1]*a.y + u[2]*d.x - u[3]*d.y;
    na.y = u[0]*a.y + u[1]*a.x + u[2]*d.y + u[3]*d.x;
    nd.x = u[4]*a.x - u[5]*a.y + u[6]*d.x - u[7]*d.y;
    nd.y = u[4]*a.y + u[5]*a.x + u[6]*d.y + u[7]*d.x;
    a = na; d = nd;
}

template <int M>
__device__ __forceinline__ void reg_gate(float2 (&amps)[16], const float u[8]) {
#pragma unroll
    for (int r = 0; r < 16; ++r)
        if (!(r & M)) pairgate(amps[r], amps[r | M], u);
}

// gate on a lane bit: mask = lane xor distance, bit = my value of that bit
__device__ __forceinline__ void lane_gate(float2 (&amps)[16], const float u[8],
                                          int mask, int bit) {
    const float c0x = bit ? u[6] : u[0];
    const float c0y = bit ? u[7] : u[1];
    const float c1x = bit ? u[4] : u[2];
    const float c1y = bit ? u[5] : u[3];
#pragma unroll
    for (int r = 0; r < 16; ++r) {
        const float mx = amps[r].x, my = amps[r].y;
        const float px = __shfl_xor(mx, mask, 64);
        const float py = __shfl_xor(my, mask, 64);
        amps[r].x = c0x*mx - c0y*my + c1x*px - c1y*py;
        amps[r].y = c0x*my + c0y*mx + c1x*py + c1y*px;
    }
}

__global__ __launch_bounds__(TPB, 4)
void qsim_kernel(const float* __restrict__ state_batch,   // [B, NW]
                 const float* __restrict__ var_params,    // [NLAYERS, NW, 3]
                 const float* __restrict__ head_w,        // [NW]
                 const float* __restrict__ head_b,        // [1]
                 float* __restrict__ out)                 // [B]
{
    __shared__ float2 psi[NSTATE];          // 128 KiB
    __shared__ float  gt[NGATES * 8];       // fused RY*RZ matrices
    __shared__ float  rxc[NW], rxs[NW];
    __shared__ float  hws[NW];
    __shared__ float  red[TPB / 64];

    const int t    = threadIdx.x;
    const int lane = t & 63;
    const int wave = t >> 6;
    const int b    = blockIdx.x;

    // ---- stage sample-angles, gate matrices, head weights into LDS ----
    if (t < NW) {
        float s, c; sincosf(0.5f * state_batch[b * NW + t], &s, &c);
        rxc[t] = c; rxs[t] = s;
    }
    if (t >= 64 && t < 64 + NGATES) {
        const int g = t - 64;                       // g = l*NW + w
        float sa, ca, sz, cz;
        sincosf(0.5f * var_params[g * 3 + 0], &sa, &ca);
        sincosf(0.5f * var_params[g * 3 + 1], &sz, &cz);
        float* G = &gt[g * 8];
        G[0] =  ca * cz; G[1] = -ca * sz;           // u00 = ca*e^{-iz}
        G[2] = -sa * cz; G[3] =  sa * sz;           // u01 = -sa*e^{-iz}
        G[4] =  sa * cz; G[5] =  sa * sz;           // u10 = sa*e^{+iz}
        G[6] =  ca * cz; G[7] =  ca * sz;           // u11 = ca*e^{+iz}
    }
    if (t >= 128 && t < 128 + NW) hws[t - 128] = head_w[t - 128];
    __syncthreads();

    // ---- RX-encoded product state directly into registers (STD layout) ----
    // amp(i) = (-i)^popcount(i) * prod_w (bit ? s_w : c_w)
    float2 amps[16];
    {
        float prodH = 1.f; int popH = 0;
#pragma unroll
        for (int w = 0; w < 10; ++w) {              // wires 0..9 from t bits
            const int bit = (t >> (9 - w)) & 1;
            prodH *= bit ? rxs[w] : rxc[w];
            popH  += bit;
        }
#pragma unroll
        for (int r = 0; r < 16; ++r) {
            float p = prodH; int pop = popH;
#pragma unroll
            for (int j = 0; j < 4; ++j) {           // wires 10..13 from r bits
                const int bit = (r >> (3 - j)) & 1;
                p   *= bit ? rxs[10 + j] : rxc[10 + j];
                pop += bit;
            }
            float2 a;
            switch (pop & 3) {
                case 0:  a = make_float2( p, 0.f); break;
                case 1:  a = make_float2(0.f, -p); break;
                case 2:  a = make_float2(-p, 0.f); break;
                default: a = make_float2(0.f,  p); break;
            }
            amps[r] = a;
        }
    }

    // ---- variational layers ----
#pragma unroll 1
    for (int l = 0; l < NLAYERS; ++l) {
        const float* Gl = &gt[l * NW * 8];
        float u[8];

        // gates wires 4..9 (lane bits, shfl): wire w -> lane mask 1<<(9-w)
        for (int w = 4; w <= 9; ++w) {
#pragma unroll
            for (int k = 0; k < 8; ++k) u[k] = Gl[w * 8 + k];
            const int m = 1 << (9 - w);
            lane_gate(amps, u, m, (lane & m) ? 1 : 0);
        }
        // gates wires 10..13 (register bits in STD): masks 8,4,2,1
#pragma unroll
        for (int k = 0; k < 8; ++k) u[k] = Gl[10 * 8 + k];
        reg_gate<8>(amps, u);
#pragma unroll
        for (int k = 0; k < 8; ++k) u[k] = Gl[11 * 8 + k];
        reg_gate<4>(amps, u);
#pragma unroll
        for (int k = 0; k < 8; ++k) u[k] = Gl[12 * 8 + k];
        reg_gate<2>(amps, u);
#pragma unroll
        for (int k = 0; k < 8; ++k) u[k] = Gl[13 * 8 + k];
        reg_gate<1>(amps, u);

        // ---- round trip 1: STD -> TRN (transpose bits [13:10] <-> [3:0]) ----
#pragma unroll
        for (int r = 0; r < 16; ++r)
            psi[swz((t << 4) | r)] = amps[r];
        __syncthreads();
#pragma unroll
        for (int r = 0; r < 16; ++r)
            amps[r] = psi[swz((r << 10) | (lane << 4) | wave)];
        __syncthreads();

        // gates wires 0..3 (register bits in TRN): wire0->8,1->4,2->2,3->1
#pragma unroll
        for (int k = 0; k < 8; ++k) u[k] = Gl[0 * 8 + k];
        reg_gate<8>(amps, u);
#pragma unroll
        for (int k = 0; k < 8; ++k) u[k] = Gl[1 * 8 + k];
        reg_gate<4>(amps, u);
#pragma unroll
        for (int k = 0; k < 8; ++k) u[k] = Gl[2 * 8 + k];
        reg_gate<2>(amps, u);
#pragma unroll
        for (int k = 0; k < 8; ++k) u[k] = Gl[3 * 8 + k];
        reg_gate<1>(amps, u);

        // CNOT(0,1),(1,2),(2,3): register swaps (control=1, target flips)
#pragma unroll
        for (int r = 0; r < 16; ++r)
            if ((r & 8) && !(r & 4)) { float2 tmp = amps[r]; amps[r] = amps[r|4]; amps[r|4] = tmp; }
#pragma unroll
        for (int r = 0; r < 16; ++r)
            if ((r & 4) && !(r & 2)) { float2 tmp = amps[r]; amps[r] = amps[r|2]; amps[r|2] = tmp; }
#pragma unroll
        for (int r = 0; r < 16; ++r)
            if ((r & 2) && !(r & 1)) { float2 tmp = amps[r]; amps[r] = amps[r|1]; amps[r|1] = tmp; }

        // CNOT(3,4): control = r bit0, target = lane bit 5 -> swap via shfl
#pragma unroll
        for (int r = 1; r < 16; r += 2) {
            amps[r].x = __shfl_xor(amps[r].x, 32, 64);
            amps[r].y = __shfl_xor(amps[r].y, 32, 64);
        }

        // ---- round trip 2: TRN -> STD, folding CNOT(4,5)..(12,13) ----
        // composite inverse perm: x = y ^ ((y>>1) & 0x1FF)
#pragma unroll
        for (int r = 0; r < 16; ++r)
            psi[swz((r << 10) | (lane << 4) | wave)] = amps[r];
        __syncthreads();
#pragma unroll
        for (int r = 0; r < 16; ++r) {
            const int y = (t << 4) | r;
            const int x = y ^ ((y >> 1) & 0x1FF);
            amps[r] = psi[swz(x)];
        }
        __syncthreads();
    }

    // ---- fused <Z> measurement + linear head ----
    float coefH = 0.f;
#pragma unroll
    for (int w = 0; w < 10; ++w)
        coefH += ((t >> (9 - w)) & 1) ? -hws[w] : hws[w];
    float acc = 0.f;
#pragma unroll
    for (int r = 0; r < 16; ++r) {
        float cl = coefH;
#pragma unroll
        for (int j = 0; j < 4; ++j)
            cl += ((r >> (3 - j)) & 1) ? -hws[10 + j] : hws[10 + j];
        acc += (amps[r].x * amps[r].x + amps[r].y * amps[r].y) * cl;
    }
#pragma unroll
    for (int off = 32; off > 0; off >>= 1)
        acc += __shfl_down(acc, off, 64);
    if (lane == 0) red[wave] = acc;
    __syncthreads();
    if (t == 0) {
        float s = 0.f;
#pragma unroll
        for (int i = 0; i < TPB / 64; ++i) s += red[i];
        out[b] = s + head_b[0];
    }
}

extern "C" void kernel_launch(void* const* d_in, const int* in_sizes, int n_in,
                              void* d_out, int out_size, void* d_ws, size_t ws_size,
                              hipStream_t stream) {
    const float* state_batch = (const float*)d_in[0];
    const float* var_params  = (const float*)d_in[1];
    const float* head_w      = (const float*)d_in[2];
    const float* head_b      = (const float*)d_in[3];
    float* out = (float*)d_out;
    qsim_kernel<<<dim3(out_size), dim3(TPB), 0, stream>>>(
        state_batch, var_params, head_w, head_b, out);
}

// Round 4
// 168.945 us; speedup vs baseline: 1.0133x; 1.0133x over previous
//
#include <hip/hip_runtime.h>

// Quantum circuit sim, register-blocked. B=256 blocks (1/CU), 1024 thr/block.
// State: 2^14 amps. Thread t holds 16 amps in registers.
//   STD layout: amp index i = (t<<4)|r   -> bits[13:4]=t, bits[3:0]=r
//   TRN layout: i = (r<<10)|(lane<<4)|wave
// Wire w <-> bit (13-w)  (PennyLane: wire 0 most significant).
//   STD: wires 0-3 = wave bits, wires 4-9 = lane bits (shfl), wires 10-13 = reg
//   TRN: wires 0-3 = reg bits,  wires 4-9 = lane bits,        wires 10-13 = wave
// LDS slot swizzle: slot(i) = i ^ ((i>>6)&15)  (bank-conflict-free for all
// four access patterns used; verified per-pattern over the 64-lane wave).
// CNOT chain (prefix-xor perm): CNOT(4,5)..(12,13) composite inverse is
// x = y ^ ((y>>1) & 0x1FF), folded into the transpose-back gather.
//
// amdgpu_waves_per_eu(4,4): R3 showed __launch_bounds__(1024,4) sets only the
// MINIMUM waves/EU — allocator still targeted 8 waves/EU, capped VGPRs at 64,
// and spilled amps[16] (150 MB scratch HBM traffic/dispatch). LDS (130 KiB)
// limits the CU to 1 block = 4 waves/EU anyway, so pin min=max=4 to get the
// full 128-VGPR budget.

#define NW      14
#define NSTATE  (1 << NW)
#define TPB     1024
#define NLAYERS 3
#define NGATES  (NLAYERS * NW)

__device__ __forceinline__ int swz(int i) { return i ^ ((i >> 6) & 15); }

// u[8] = {u00x,u00y, u01x,u01y, u10x,u10y, u11x,u11y}
__device__ __forceinline__ void pairgate(float2& a, float2& d, const float u[8]) {
    float2 na, nd;
    na.x = u[0]*a.x - u[1]*a.y + u[2]*d.x - u[3]*d.y;
    na.y = u[0]*a.y + u[1]*a.x + u[2]*d.y + u[3]*d.x;
    nd.x = u[4]*a.x - u[5]*a.y + u[6]*d.x - u[7]*d.y;
    nd.y = u[4]*a.y + u[5]*a.x + u[6]*d.y + u[7]*d.x;
    a = na; d = nd;
}

template <int M>
__device__ __forceinline__ void reg_gate(float2 (&amps)[16], const float u[8]) {
#pragma unroll
    for (int r = 0; r < 16; ++r)
        if (!(r & M)) pairgate(amps[r], amps[r | M], u);
}

// gate on a lane bit: mask = lane xor distance, bit = my value of that bit
__device__ __forceinline__ void lane_gate(float2 (&amps)[16], const float u[8],
                                          int mask, int bit) {
    const float c0x = bit ? u[6] : u[0];
    const float c0y = bit ? u[7] : u[1];
    const float c1x = bit ? u[4] : u[2];
    const float c1y = bit ? u[5] : u[3];
#pragma unroll
    for (int r = 0; r < 16; ++r) {
        const float mx = amps[r].x, my = amps[r].y;
        const float px = __shfl_xor(mx, mask, 64);
        const float py = __shfl_xor(my, mask, 64);
        amps[r].x = c0x*mx - c0y*my + c1x*px - c1y*py;
        amps[r].y = c0x*my + c0y*mx + c1x*py + c1y*px;
    }
}

__global__ void
__launch_bounds__(TPB)
__attribute__((amdgpu_waves_per_eu(4, 4)))
qsim_kernel(const float* __restrict__ state_batch,   // [B, NW]
            const float* __restrict__ var_params,    // [NLAYERS, NW, 3]
            const float* __restrict__ head_w,        // [NW]
            const float* __restrict__ head_b,        // [1]
            float* __restrict__ out)                 // [B]
{
    __shared__ float2 psi[NSTATE];          // 128 KiB
    __shared__ float  gt[NGATES * 8];       // fused RY*RZ matrices
    __shared__ float  rxc[NW], rxs[NW];
    __shared__ float  hws[NW];
    __shared__ float  red[TPB / 64];

    const int t    = threadIdx.x;
    const int lane = t & 63;
    const int wave = t >> 6;
    const int b    = blockIdx.x;

    // ---- stage sample-angles, gate matrices, head weights into LDS ----
    if (t < NW) {
        float s, c; sincosf(0.5f * state_batch[b * NW + t], &s, &c);
        rxc[t] = c; rxs[t] = s;
    }
    if (t >= 64 && t < 64 + NGATES) {
        const int g = t - 64;                       // g = l*NW + w
        float sa, ca, sz, cz;
        sincosf(0.5f * var_params[g * 3 + 0], &sa, &ca);
        sincosf(0.5f * var_params[g * 3 + 1], &sz, &cz);
        float* G = &gt[g * 8];
        G[0] =  ca * cz; G[1] = -ca * sz;           // u00 = ca*e^{-iz}
        G[2] = -sa * cz; G[3] =  sa * sz;           // u01 = -sa*e^{-iz}
        G[4] =  sa * cz; G[5] =  sa * sz;           // u10 = sa*e^{+iz}
        G[6] =  ca * cz; G[7] =  ca * sz;           // u11 = ca*e^{+iz}
    }
    if (t >= 128 && t < 128 + NW) hws[t - 128] = head_w[t - 128];
    __syncthreads();

    // ---- RX-encoded product state directly into registers (STD layout) ----
    // amp(i) = (-i)^popcount(i) * prod_w (bit ? s_w : c_w)
    float2 amps[16];
    {
        float prodH = 1.f; int popH = 0;
#pragma unroll
        for (int w = 0; w < 10; ++w) {              // wires 0..9 from t bits
            const int bit = (t >> (9 - w)) & 1;
            prodH *= bit ? rxs[w] : rxc[w];
            popH  += bit;
        }
#pragma unroll
        for (int r = 0; r < 16; ++r) {
            float p = prodH; int pop = popH;
#pragma unroll
            for (int j = 0; j < 4; ++j) {           // wires 10..13 from r bits
                const int bit = (r >> (3 - j)) & 1;
                p   *= bit ? rxs[10 + j] : rxc[10 + j];
                pop += bit;
            }
            float2 a;
            switch (pop & 3) {
                case 0:  a = make_float2( p, 0.f); break;
                case 1:  a = make_float2(0.f, -p); break;
                case 2:  a = make_float2(-p, 0.f); break;
                default: a = make_float2(0.f,  p); break;
            }
            amps[r] = a;
        }
    }

    // ---- variational layers ----
#pragma unroll 1
    for (int l = 0; l < NLAYERS; ++l) {
        const float* Gl = &gt[l * NW * 8];
        float u[8];

        // gates wires 4..9 (lane bits, shfl): wire w -> lane mask 1<<(9-w)
        for (int w = 4; w <= 9; ++w) {
#pragma unroll
            for (int k = 0; k < 8; ++k) u[k] = Gl[w * 8 + k];
            const int m = 1 << (9 - w);
            lane_gate(amps, u, m, (lane & m) ? 1 : 0);
        }
        // gates wires 10..13 (register bits in STD): masks 8,4,2,1
#pragma unroll
        for (int k = 0; k < 8; ++k) u[k] = Gl[10 * 8 + k];
        reg_gate<8>(amps, u);
#pragma unroll
        for (int k = 0; k < 8; ++k) u[k] = Gl[11 * 8 + k];
        reg_gate<4>(amps, u);
#pragma unroll
        for (int k = 0; k < 8; ++k) u[k] = Gl[12 * 8 + k];
        reg_gate<2>(amps, u);
#pragma unroll
        for (int k = 0; k < 8; ++k) u[k] = Gl[13 * 8 + k];
        reg_gate<1>(amps, u);

        // ---- round trip 1: STD -> TRN (transpose bits [13:10] <-> [3:0]) ----
#pragma unroll
        for (int r = 0; r < 16; ++r)
            psi[swz((t << 4) | r)] = amps[r];
        __syncthreads();
#pragma unroll
        for (int r = 0; r < 16; ++r)
            amps[r] = psi[swz((r << 10) | (lane << 4) | wave)];
        __syncthreads();

        // gates wires 0..3 (register bits in TRN): wire0->8,1->4,2->2,3->1
#pragma unroll
        for (int k = 0; k < 8; ++k) u[k] = Gl[0 * 8 + k];
        reg_gate<8>(amps, u);
#pragma unroll
        for (int k = 0; k < 8; ++k) u[k] = Gl[1 * 8 + k];
        reg_gate<4>(amps, u);
#pragma unroll
        for (int k = 0; k < 8; ++k) u[k] = Gl[2 * 8 + k];
        reg_gate<2>(amps, u);
#pragma unroll
        for (int k = 0; k < 8; ++k) u[k] = Gl[3 * 8 + k];
        reg_gate<1>(amps, u);

        // CNOT(0,1),(1,2),(2,3): register swaps (control=1, target flips)
#pragma unroll
        for (int r = 0; r < 16; ++r)
            if ((r & 8) && !(r & 4)) { float2 tmp = amps[r]; amps[r] = amps[r|4]; amps[r|4] = tmp; }
#pragma unroll
        for (int r = 0; r < 16; ++r)
            if ((r & 4) && !(r & 2)) { float2 tmp = amps[r]; amps[r] = amps[r|2]; amps[r|2] = tmp; }
#pragma unroll
        for (int r = 0; r < 16; ++r)
            if ((r & 2) && !(r & 1)) { float2 tmp = amps[r]; amps[r] = amps[r|1]; amps[r|1] = tmp; }

        // CNOT(3,4): control = r bit0, target = lane bit 5 -> swap via shfl
#pragma unroll
        for (int r = 1; r < 16; r += 2) {
            amps[r].x = __shfl_xor(amps[r].x, 32, 64);
            amps[r].y = __shfl_xor(amps[r].y, 32, 64);
        }

        // ---- round trip 2: TRN -> STD, folding CNOT(4,5)..(12,13) ----
        // composite inverse perm: x = y ^ ((y>>1) & 0x1FF)
#pragma unroll
        for (int r = 0; r < 16; ++r)
            psi[swz((r << 10) | (lane << 4) | wave)] = amps[r];
        __syncthreads();
#pragma unroll
        for (int r = 0; r < 16; ++r) {
            const int y = (t << 4) | r;
            const int x = y ^ ((y >> 1) & 0x1FF);
            amps[r] = psi[swz(x)];
        }
        __syncthreads();
    }

    // ---- fused <Z> measurement + linear head ----
    float coefH = 0.f;
#pragma unroll
    for (int w = 0; w < 10; ++w)
        coefH += ((t >> (9 - w)) & 1) ? -hws[w] : hws[w];
    float acc = 0.f;
#pragma unroll
    for (int r = 0; r < 16; ++r) {
        float cl = coefH;
#pragma unroll
        for (int j = 0; j < 4; ++j)
            cl += ((r >> (3 - j)) & 1) ? -hws[10 + j] : hws[10 + j];
        acc += (amps[r].x * amps[r].x + amps[r].y * amps[r].y) * cl;
    }
#pragma unroll
    for (int off = 32; off > 0; off >>= 1)
        acc += __shfl_down(acc, off, 64);
    if (lane == 0) red[wave] = acc;
    __syncthreads();
    if (t == 0) {
        float s = 0.f;
#pragma unroll
        for (int i = 0; i < TPB / 64; ++i) s += red[i];
        out[b] = s + head_b[0];
    }
}

extern "C" void kernel_launch(void* const* d_in, const int* in_sizes, int n_in,
                              void* d_out, int out_size, void* d_ws, size_t ws_size,
                              hipStream_t stream) {
    const float* state_batch = (const float*)d_in[0];
    const float* var_params  = (const float*)d_in[1];
    const float* head_w      = (const float*)d_in[2];
    const float* head_b      = (const float*)d_in[3];
    float* out = (float*)d_out;
    qsim_kernel<<<dim3(out_size), dim3(TPB), 0, stream>>>(
        state_batch, var_params, head_w, head_b, out);
}